// Round 4
// baseline (135.971 us; speedup 1.0000x reference)
//
#include <hip/hip_runtime.h>
#include <stdint.h>

#define NCLS   80
#define HWTOT  21824
#define MBOX   100

// flat f32 output layout (return-order concat)
#define REG_OFF 28633088ull   // 16*21824*82
#define IND_OFF 30728192ull   // + 16*21824*6
#define NB_OFF  31077376ull   // + 16*21824

__global__ __launch_bounds__(256)
void sapd_targets(const float* __restrict__ gt, float* __restrict__ out)
{
    const int tid = threadIdx.x;
    const int c   = blockIdx.x;   // chunk id within batch, 0..85
    const int b   = blockIdx.y;   // batch 0..15

    // chunk -> (level, pixel0, level base). Chunks never cross level bounds.
    int lvl, pix0, base;
    if      (c < 64) { lvl = 0; pix0 = c << 8;        base = 0;     }
    else if (c < 80) { lvl = 1; pix0 = (c - 64) << 8; base = 16384; }
    else if (c < 84) { lvl = 2; pix0 = (c - 80) << 8; base = 20480; }
    else if (c < 85) { lvl = 3; pix0 = 0;             base = 21504; }
    else             { lvl = 4; pix0 = 0;             base = 21760; }

    const int   l2fw   = 7 - lvl;        // fw: 128,64,32,16,8
    const int   fw     = 1 << l2fw;
    const float fs     = (float)(8 << lvl);
    const int   chunkN = (lvl == 4) ? 64 : 256;

    const size_t rowbase = (size_t)b * HWTOT + base + pix0;  // always even

    __shared__ float4   sBox[MBOX];    // original image-space coords
    __shared__ int      sLab[MBOX];
    __shared__ float2   sCull[MBOX];   // {packed bounds as float bits, area}
    __shared__ int      sOrig[MBOX];
    __shared__ float2   sSP[256];      // {soft, posf} per row
    __shared__ int      sTgt[256];     // label col or -1 per row
    __shared__ float    rReg[256 * 4];

    if (tid >= 64) {
        // ---- waves 1-3 (192 threads): zero this block's cls chunk from t~0.
        // The HBM write pipe is fed immediately; wave 0's compute runs under
        // this drain. rowbase even -> 16B aligned; (82*chunkN)%4==0.
        float4* o4 = (float4*)(out + rowbase * 82);
        const int n4 = (chunkN * 82) >> 2;            // 5248 or 1312
        const float4 z = make_float4(0.0f, 0.0f, 0.0f, 0.0f);
        for (int i = tid - 64; i < n4; i += 192) o4[i] = z;
    } else {
        // ---- wave 0: gt load is its FIRST VMEM op (no stores queued ahead of
        // it on this wave's vmcnt), then register-resident cull + argmin.
        // Everything here is wave-internal: no barrier until the single one below.
        const int lane = tid;
        const int ry0 = pix0 >> l2fw;
        const int ry1 = ry0 + (chunkN >> l2fw);
        int n0 = 0;
        int nvalid = 0;
        #pragma unroll
        for (int h = 0; h < 2; ++h) {
            const int m = h * 64 + lane;
            bool pred = false, valid = false;
            uint32_t bb = 0;
            float area = 0.0f;
            if (m < MBOX) {
                const float* g = gt + ((size_t)b * MBOX + m) * 5;
                float x1 = g[0], y1 = g[1], x2 = g[2], y2 = g[3], lab = g[4];
                valid = (fabsf(x1) + fabsf(y1) + fabsf(x2) + fabsf(y2)) > 0.0f;
                area  = (x2 - x1) * (y2 - y1);
                float bx1 = x1 / fs, by1 = y1 / fs, bx2 = x2 / fs, by2 = y2 / fs;
                float cx = (bx1 + bx2) * 0.5f, cy = (by1 + by2) * 0.5f;
                float hw = (bx2 - bx1) * 0.5f * 0.2f, hh = (by2 - by1) * 0.5f * 0.2f;
                float px1 = fmaxf(floorf(cx - hw), 0.0f);
                float py1 = fmaxf(floorf(cy - hh), 0.0f);
                float px2 = fminf(ceilf(cx + hw), (float)fw);
                float py2 = fminf(ceilf(cy + hh), (float)fw);
                int ix1 = (int)px1, iy1 = (int)py1, ix2 = (int)px2, iy2 = (int)py2;
                bb = (uint32_t)ix1 | ((uint32_t)iy1 << 8) |
                     ((uint32_t)ix2 << 16) | ((uint32_t)iy2 << 24);
                pred = valid && (ix2 > ix1) && (iy2 > ry0) && (iy1 < ry1);
                sBox[m] = make_float4(x1, y1, x2, y2);
                sLab[m] = (int)lab;
            }
            unsigned long long mk = __ballot(pred);
            unsigned long long vk = __ballot(valid);
            if (pred) {
                int p = n0 + __popcll(mk & ((1ull << lane) - 1ull));
                sCull[p] = make_float2(__uint_as_float(bb), area);  // orig order kept
                sOrig[p] = m;
            }
            n0     += __popcll(mk);   // uniform across lanes
            nvalid += __popcll(vk);
        }
        if (lvl == 4 && lane == 0) out[NB_OFF + b] = (float)nvalid;

        // argmin: 4 rows per lane (row = lane + j*64), LDS read amortized 4x.
        // For lvl 4 (chunkN=64) rows j>=1 are garbage but never escape: all
        // global stores / fixup readers are guarded by row < chunkN.
        int px_[4], py_[4];
        float bestA[4];
        int   bestI[4];
        #pragma unroll
        for (int j = 0; j < 4; ++j) {
            int p = pix0 + lane + j * 64;
            px_[j] = p & (fw - 1);
            py_[j] = p >> l2fw;
            bestA[j] = 1e30f;
            bestI[j] = -1;
        }
        for (int i = 0; i < n0; ++i) {
            float2 e = sCull[i];
            uint32_t bb = __float_as_uint(e.x);
            int x1 = bb & 255, y1 = (bb >> 8) & 255, x2 = (bb >> 16) & 255, y2 = bb >> 24;
            #pragma unroll
            for (int j = 0; j < 4; ++j) {
                bool hit = (px_[j] >= x1) & (px_[j] < x2) & (py_[j] >= y1) & (py_[j] < y2);
                bool upd = hit & (e.y < bestA[j]);   // strict < keeps first on ties
                bestA[j] = upd ? e.y : bestA[j];
                bestI[j] = upd ? i  : bestI[j];
            }
        }
        #pragma unroll
        for (int j = 0; j < 4; ++j) {
            const int row = lane + j * 64;
            bool pos = bestI[j] >= 0;
            int orig = pos ? sOrig[bestI[j]] : 0;
            float4 bx = sBox[orig];
            float sx = ((float)px_[j] + 0.5f) * fs;
            float sy = ((float)py_[j] + 0.5f) * fs;
            float l  = sx - bx.x, t = sy - bx.y, r = bx.z - sx, bt = bx.w - sy;
            float inv4s = 1.0f / (4.0f * fs);   // power of two: exact vs ref divide
            float posf  = pos ? 1.0f : 0.0f;
            const float eps = 1e-6f;
            float a1 = fminf(l, r) / fmaxf(fmaxf(l, r), eps);
            a1 = fminf(fmaxf(a1, 0.0f), 1.0f);
            float a2 = fminf(t, bt) / fmaxf(fmaxf(t, bt), eps);
            a2 = fminf(fmaxf(a2, 0.0f), 1.0f);
            float cent = sqrtf(a1 * a2);
            float soft = pos ? cent : 1.0f;
            sSP[row]  = make_float2(soft, posf);
            sTgt[row] = pos ? sLab[orig] : -1;
            rReg[row * 4 + 0] = l  * inv4s * posf;
            rReg[row * 4 + 1] = t  * inv4s * posf;
            rReg[row * 4 + 2] = r  * inv4s * posf;
            rReg[row * 4 + 3] = bt * inv4s * posf;
            if (row < chunkN)
                out[IND_OFF + rowbase + row] = pos ? (float)orig : -1.0f;
        }
    }

    // ---- the ONLY barrier: drains waves 1-3's zeros (vmcnt(0)) to the L2
    // coherence point AND publishes wave 0's LDS results.
    __syncthreads();

    // ---- sparse per-row cls fixup into L2-warm zeroed lines ----
    // cls row = 80 one-hot + soft + posf:
    //   cols 80..81 <- {soft, posf}  (row*82 even -> +80 is 8B-aligned)
    //   col  tgt    <- 1.0f when pos
    if (tid < chunkN) {
        float2 sp = sSP[tid];
        const size_t row0 = (rowbase + (size_t)tid) * 82ull;
        *(float2*)(out + row0 + 80) = sp;
        int tg = sTgt[tid];
        if (tg >= 0) out[row0 + tg] = 1.0f;
    }

    // ---- reg region: contiguous float4 fill from LDS ----
    {
        float4* o4 = (float4*)(out + REG_OFF + rowbase * 6);   // 16B-aligned
        const int n4 = (chunkN * 6) >> 2;   // 384 or 96
        for (int i = tid; i < n4; i += 256) {
            int idx = i << 2;
            float v[4];
            #pragma unroll
            for (int k = 0; k < 4; ++k) {
                int id  = idx + k;
                int row = (int)((unsigned)id / 6u);
                int col = id - row * 6;
                float2 m = sSP[row];
                v[k] = (col < 4) ? rReg[row * 4 + col] : ((col == 4) ? m.x : m.y);
            }
            o4[i] = make_float4(v[0], v[1], v[2], v[3]);
        }
    }
}

extern "C" void kernel_launch(void* const* d_in, const int* in_sizes, int n_in,
                              void* d_out, int out_size, void* d_ws, size_t ws_size,
                              hipStream_t stream)
{
    const float* gt = (const float*)d_in[0];
    float* out = (float*)d_out;
    sapd_targets<<<dim3(86, 16), 256, 0, stream>>>(gt, out);
}

// Round 5
// 127.224 us; speedup vs baseline: 1.0687x; 1.0687x over previous
//
#include <hip/hip_runtime.h>
#include <stdint.h>

#define NCLS   80
#define HWTOT  21824
#define MBOX   100

// flat f32 output layout (return-order concat)
#define REG_OFF 28633088ull   // 16*21824*82
#define IND_OFF 30728192ull   // + 16*21824*6
#define NB_OFF  31077376ull   // + 16*21824

__global__ __launch_bounds__(256)
void sapd_targets(const float* __restrict__ gt, float* __restrict__ out)
{
    const int tid  = threadIdx.x;
    const int w    = tid >> 6;        // wave 0..3
    const int lane = tid & 63;
    const int c    = blockIdx.x;      // chunk id within batch, 0..85
    const int b    = blockIdx.y;      // batch 0..15

    // chunk -> (level, pixel0, level base). Chunks never cross level bounds.
    int lvl, pix0, base;
    if      (c < 64) { lvl = 0; pix0 = c << 8;        base = 0;     }
    else if (c < 80) { lvl = 1; pix0 = (c - 64) << 8; base = 16384; }
    else if (c < 84) { lvl = 2; pix0 = (c - 80) << 8; base = 20480; }
    else if (c < 85) { lvl = 3; pix0 = 0;             base = 21504; }
    else             { lvl = 4; pix0 = 0;             base = 21760; }

    const int   l2fw   = 7 - lvl;        // fw: 128,64,32,16,8
    const int   fw     = 1 << l2fw;
    const float fs     = (float)(8 << lvl);
    const int   chunkN = (lvl == 4) ? 64 : 256;

    // Each wave owns rows [w*64, w*64+64). lvl-4 blocks: waves 1-3 exit now.
    if (w * 64 >= chunkN) return;

    const size_t rowbase = (size_t)b * HWTOT + base + pix0;  // even
    const int    row     = w * 64 + lane;     // this lane's row in the chunk
    const int    p0      = pix0 + w * 64;     // wave's first pixel (mult of 64)

    // per-wave LDS copies -> zero __syncthreads in the whole kernel
    __shared__ float2 sCull[4][MBOX];   // {packed bounds as float bits, area}
    __shared__ int    sOrig[4][MBOX];
    __shared__ float4 sBox [4][MBOX];   // original image-space coords
    __shared__ int    sLab [4][MBOX];
    __shared__ float  sReg [4][64 * 6]; // {l,t,r,b,soft,posf} per row

    // wave's pixel band for the cull (tighter than the 256-px chunk band)
    const int ry0 = p0 >> l2fw;
    const int ry1 = ((p0 + 63) >> l2fw) + 1;
    int pxlo, pxhi;
    if (fw >= 64) { pxlo = p0 & (fw - 1); pxhi = pxlo + 63; }  // 64 px in one row
    else          { pxlo = 0;             pxhi = fw - 1;    }  // full rows

    // ---- 1. gt loads: the wave's FIRST VMEM ops (nothing queued ahead on vmcnt)
    const float* g0 = gt + ((size_t)b * MBOX + lane) * 5;
    float ax1 = g0[0], ay1 = g0[1], ax2 = g0[2], ay2 = g0[3], alab = g0[4];
    const int  mb   = 64 + lane;
    const bool hasb = mb < MBOX;
    float bx1 = 0, by1 = 0, bx2 = 0, by2 = 0, blab = 0;
    if (hasb) {
        const float* g1 = gt + ((size_t)b * MBOX + mb) * 5;
        bx1 = g1[0]; by1 = g1[1]; bx2 = g1[2]; by2 = g1[3]; blab = g1[4];
    }

    // ---- 2. per-wave register cull (ballot-compact, original order kept) ----
    int nW = 0, nvalid = 0;
    {   // half 0: m = lane (always < MBOX)
        bool valid = (fabsf(ax1) + fabsf(ay1) + fabsf(ax2) + fabsf(ay2)) > 0.0f;
        float area = (ax2 - ax1) * (ay2 - ay1);
        float q1 = ax1 / fs, q2 = ay1 / fs, q3 = ax2 / fs, q4 = ay2 / fs;
        float cx = (q1 + q3) * 0.5f, cy = (q2 + q4) * 0.5f;
        float hw = (q3 - q1) * 0.5f * 0.2f, hh = (q4 - q2) * 0.5f * 0.2f;
        int ix1 = (int)fmaxf(floorf(cx - hw), 0.0f);
        int iy1 = (int)fmaxf(floorf(cy - hh), 0.0f);
        int ix2 = (int)fminf(ceilf(cx + hw), (float)fw);
        int iy2 = (int)fminf(ceilf(cy + hh), (float)fw);
        uint32_t bb = (uint32_t)ix1 | ((uint32_t)iy1 << 8) |
                      ((uint32_t)ix2 << 16) | ((uint32_t)iy2 << 24);
        bool pred = valid && (ix2 > ix1) && (iy2 > ry0) && (iy1 < ry1)
                          && (ix1 <= pxhi) && (ix2 > pxlo);
        sBox[w][lane] = make_float4(ax1, ay1, ax2, ay2);
        sLab[w][lane] = (int)alab;
        unsigned long long mk = __ballot(pred);
        nvalid += __popcll(__ballot(valid));
        if (pred) {
            int pp = __popcll(mk & ((1ull << lane) - 1ull));
            sCull[w][pp] = make_float2(__uint_as_float(bb), area);
            sOrig[w][pp] = lane;
        }
        nW += __popcll(mk);
    }
    {   // half 1: m = 64 + lane, guarded
        bool valid = false, pred = false;
        uint32_t bb = 0;
        float area = 0.0f;
        if (hasb) {
            valid = (fabsf(bx1) + fabsf(by1) + fabsf(bx2) + fabsf(by2)) > 0.0f;
            area  = (bx2 - bx1) * (by2 - by1);
            float q1 = bx1 / fs, q2 = by1 / fs, q3 = bx2 / fs, q4 = by2 / fs;
            float cx = (q1 + q3) * 0.5f, cy = (q2 + q4) * 0.5f;
            float hw = (q3 - q1) * 0.5f * 0.2f, hh = (q4 - q2) * 0.5f * 0.2f;
            int ix1 = (int)fmaxf(floorf(cx - hw), 0.0f);
            int iy1 = (int)fmaxf(floorf(cy - hh), 0.0f);
            int ix2 = (int)fminf(ceilf(cx + hw), (float)fw);
            int iy2 = (int)fminf(ceilf(cy + hh), (float)fw);
            bb = (uint32_t)ix1 | ((uint32_t)iy1 << 8) |
                 ((uint32_t)ix2 << 16) | ((uint32_t)iy2 << 24);
            pred = valid && (ix2 > ix1) && (iy2 > ry0) && (iy1 < ry1)
                         && (ix1 <= pxhi) && (ix2 > pxlo);
            sBox[w][mb] = make_float4(bx1, by1, bx2, by2);
            sLab[w][mb] = (int)blab;
        }
        unsigned long long mk = __ballot(pred);
        nvalid += __popcll(__ballot(valid));
        if (pred) {
            int pp = nW + __popcll(mk & ((1ull << lane) - 1ull));
            sCull[w][pp] = make_float2(__uint_as_float(bb), area);
            sOrig[w][pp] = mb;
        }
        nW += __popcll(mk);
    }
    // num_boxes (lvl-4 block has only wave 0 alive; region never zeroed)
    if (lvl == 4 && lane == 0) out[NB_OFF + b] = (float)nvalid;

    // ---- 3. zero stream of this wave's OWN 64 cls rows (21 KB) ----
    // Pinned between sched_barriers: cannot hoist above the gt loads (v3 bug)
    // nor sink below argmin. (rowbase + w*64)*82 is a multiple of 4 -> 16B ok.
    __builtin_amdgcn_sched_barrier(0);
    {
        float4* o4 = (float4*)(out + (rowbase + (size_t)(w * 64)) * 82ull);
        const float4 z = make_float4(0.0f, 0.0f, 0.0f, 0.0f);
        for (int i = lane; i < 1312; i += 64) o4[i] = z;   // 64*82/4
    }
    __builtin_amdgcn_sched_barrier(0);

    // ---- 4. argmin over the wave's culled list (runs under the store drain) ----
    const int px = (pix0 + row) & (fw - 1);
    const int py = (pix0 + row) >> l2fw;
    float bestA = 1e30f; int bestI = -1;
    for (int i = 0; i < nW; ++i) {
        float2 e = sCull[w][i];
        uint32_t bbv = __float_as_uint(e.x);
        int x1 = bbv & 255, y1 = (bbv >> 8) & 255, x2 = (bbv >> 16) & 255, y2 = bbv >> 24;
        bool hit = (px >= x1) & (px < x2) & (py >= y1) & (py < y2);
        bool upd = hit & (e.y < bestA);   // strict < keeps first (orig order) on ties
        bestA = upd ? e.y : bestA;
        bestI = upd ? i : bestI;
    }

    // ---- 5. target math (still under the drain) ----
    bool pos  = bestI >= 0;
    int  orig = pos ? sOrig[w][bestI] : 0;
    float4 bx = sBox[w][orig];
    float sx = ((float)px + 0.5f) * fs;
    float sy = ((float)py + 0.5f) * fs;
    float l  = sx - bx.x, t = sy - bx.y, r = bx.z - sx, bt = bx.w - sy;
    float inv4s = 1.0f / (4.0f * fs);   // power of two: exact vs reference divide
    float posf  = pos ? 1.0f : 0.0f;
    const float eps = 1e-6f;
    float a1 = fminf(l, r) / fmaxf(fmaxf(l, r), eps);
    a1 = fminf(fmaxf(a1, 0.0f), 1.0f);
    float a2 = fminf(t, bt) / fmaxf(fmaxf(t, bt), eps);
    a2 = fminf(fmaxf(a2, 0.0f), 1.0f);
    float cent = sqrtf(a1 * a2);
    float soft = pos ? cent : 1.0f;
    int   tgt  = pos ? sLab[w][orig] : -1;
    {
        float* rr = &sReg[w][lane * 6];
        rr[0] = l  * inv4s * posf;
        rr[1] = t  * inv4s * posf;
        rr[2] = r  * inv4s * posf;
        rr[3] = bt * inv4s * posf;
        rr[4] = soft;
        rr[5] = posf;
    }
    // ind row (region never zeroed -> no ordering needed; issue early)
    out[IND_OFF + rowbase + row] = pos ? (float)orig : -1.0f;

    // ---- 6. wave-level drain: THIS wave's zeros reach the coherence point.
    // Not a block barrier - other waves keep streaming independently.
    asm volatile("s_waitcnt vmcnt(0)" ::: "memory");

    // ---- 7. sparse patches into the wave's own (L2-warm) zeroed rows ----
    // cls row = 80 one-hot + soft + posf. (rowbase+row)*82 even -> +80 8B-aligned.
    {
        const size_t row0 = (rowbase + (size_t)row) * 82ull;
        *(float2*)(out + row0 + 80) = make_float2(soft, posf);
        if (tgt >= 0) out[row0 + tgt] = 1.0f;
    }

    // ---- 8. reg region: contiguous float4 fill from wave-local LDS ----
    {
        float4* o4 = (float4*)(out + REG_OFF + (rowbase + (size_t)(w * 64)) * 6ull);
        const float4* s4 = (const float4*)&sReg[w][0];
        for (int i = lane; i < 96; i += 64) o4[i] = s4[i];  // 64*6/4
    }
}

extern "C" void kernel_launch(void* const* d_in, const int* in_sizes, int n_in,
                              void* d_out, int out_size, void* d_ws, size_t ws_size,
                              hipStream_t stream)
{
    const float* gt = (const float*)d_in[0];
    float* out = (float*)d_out;
    sapd_targets<<<dim3(86, 16), 256, 0, stream>>>(gt, out);
}